// Round 4
// baseline (78.410 us; speedup 1.0000x reference)
//
#include <hip/hip_runtime.h>

// SidewaysTime: out = concat(flat, tril(outer(flat,flat))) per batch sample.
// B=32, N=2048. Output = 268.8 MB fp32 -> pure store-BW bound.
// Fill-buffer ceiling on this harness: ~6.8-7.1 TB/s; we're at 5.92.
//
// Row mapping: tril row i is a contiguous run of length i+1 at tri(i).
// Block p handles rows p and N-1-p (combined 2049 elems, constant).
// This round: NON-TEMPORAL stores (stream 268.8 MB past L2, keep the 256 KB
// input resident) + unaligned 16B vector loads for the operands.

#define BATCH      32
#define NFEAT      2048
#define TRI_COUNT  (NFEAT * (NFEAT + 1) / 2)      // 2,098,176
#define PER_BATCH  (NFEAT + TRI_COUNT)            // 2,100,224
#define PAIRS      (NFEAT / 2)                    // 1024 row-pairs per batch

typedef float f4v  __attribute__((ext_vector_type(4)));            // 16B aligned
typedef float f4vu __attribute__((ext_vector_type(4), aligned(4))); // align-4 load

__device__ __forceinline__ void do_row(const float* __restrict__ f,
                                       float* __restrict__ otri,  // ob + NFEAT
                                       int i, int t) {
    const float fi = f[i];                         // wave-uniform
    const int   S  = (i * (i + 1)) >> 1;           // row start within tril
    float* __restrict__ orow = otri + S;
    const int   L  = i + 1;                        // row length
    int h = (4 - (S & 3)) & 3;                     // head elems to 16B align
    if (h > L) h = L;
    if (t < h) __builtin_nontemporal_store(fi * f[t], orow + t);
    const int V = (L - h) >> 2;                    // float4 groups
    for (int v = t; v < V; v += 256) {
        const int j = h + (v << 2);
        f4vu a = *reinterpret_cast<const f4vu*>(f + j);  // dwordx4, align 4
        f4v  o;
        o[0] = fi * a[0]; o[1] = fi * a[1];
        o[2] = fi * a[2]; o[3] = fi * a[3];
        __builtin_nontemporal_store(o, reinterpret_cast<f4v*>(orow + j));
    }
    const int done = h + (V << 2);
    if (t < L - done) {                            // tail (<=3)
        const int j = done + t;
        __builtin_nontemporal_store(fi * f[j], orow + j);
    }
}

__global__ void __launch_bounds__(256)
sideways_rows_nt_kernel(const float* __restrict__ in, float* __restrict__ out) {
    const int blk = blockIdx.x;
    const int b   = blk >> 10;                     // / PAIRS
    const int p   = blk & (PAIRS - 1);
    const int t   = threadIdx.x;

    const float* __restrict__ f    = in + b * NFEAT;
    float* __restrict__       ob   = out + b * PER_BATCH;
    float* __restrict__       otri = ob + NFEAT;

    if (p == 0) {                                  // linear part, aligned
        for (int v = t; v < NFEAT / 4; v += 256) {
            f4v x = reinterpret_cast<const f4v*>(f)[v];
            __builtin_nontemporal_store(x, reinterpret_cast<f4v*>(ob) + v);
        }
    }

    do_row(f, otri, p, t);                         // short row
    do_row(f, otri, NFEAT - 1 - p, t);             // long row
}

extern "C" void kernel_launch(void* const* d_in, const int* in_sizes, int n_in,
                              void* d_out, int out_size, void* d_ws, size_t ws_size,
                              hipStream_t stream) {
    const float* in  = (const float*)d_in[0];
    float*       out = (float*)d_out;
    const int grid = BATCH * PAIRS;                // 32768 blocks
    hipLaunchKernelGGL(sideways_rows_nt_kernel, dim3(grid), dim3(256), 0,
                       stream, in, out);
}

// Round 5
// 74.375 us; speedup vs baseline: 1.0543x; 1.0543x over previous
//
#include <hip/hip_runtime.h>

// SidewaysTime: out = concat(flat, tril(outer(flat,flat))) per batch sample.
// B=32, N=2048. Output = 268.8 MB fp32 -> pure store-BW bound.
// Fill ceiling on this harness: ~6.8-7.1 TB/s; round-3 row kernel: 5.92 TB/s.
//
// Flat chunk-walker: each block owns a CONTIGUOUS chunk of the tril output
// (fill-kernel-like store stream: all float4, all aligned, no per-row
// head/tail scalars). (i,j) computed once per thread (sqrt + exact fixup),
// then walked incrementally across the 1024-element per-iteration jumps.
// NOTE r4 lesson: NO nontemporal stores (nt regressed 45->78us on gfx950).

#define BATCH      32
#define NFEAT      2048
#define TRI_COUNT  (NFEAT * (NFEAT + 1) / 2)      // 2,098,176
#define PER_BATCH  (NFEAT + TRI_COUNT)            // 2,100,224
#define TRI4       (TRI_COUNT / 4)                // 524,544 float4s per batch
#define CHUNKS     64                             // chunks per batch
#define CHUNK4     (TRI4 / CHUNKS)                // 8,196 float4s (exact)

__device__ __forceinline__ int tri(int i) { return (i * (i + 1)) >> 1; }

__global__ void __launch_bounds__(256)
sideways_walk_kernel(const float* __restrict__ in, float* __restrict__ out) {
    const int blk = blockIdx.x;
    const int b   = blk >> 6;                      // / CHUNKS
    const int c   = blk & (CHUNKS - 1);
    const int t   = threadIdx.x;

    const float* __restrict__ f    = in + b * NFEAT;
    float* __restrict__       ob   = out + b * PER_BATCH;
    float* __restrict__       otri = ob + NFEAT;

    if (c == 0) {                                  // linear part (512 float4s)
        for (int v = t; v < NFEAT / 4; v += 256)
            reinterpret_cast<float4*>(ob)[v] =
                reinterpret_cast<const float4*>(f)[v];
    }

    int idx4      = c * CHUNK4 + t;                // float4 index in batch tril
    const int end = (c + 1) * CHUNK4;
    int te        = idx4 << 2;                     // element index in tril

    // one-time row init: largest i with tri(i) <= te  (sqrt + exact fixup;
    // 8*te+1 slightly exceeds 2^24 so the while-fixups are required)
    int i = (int)((sqrtf((float)(8 * te) + 1.0f) - 1.0f) * 0.5f);
    if (i < 0) i = 0;
    if (i > NFEAT - 1) i = NFEAT - 1;
    while (tri(i) > te) --i;
    while (tri(i + 1) <= te) ++i;
    int   rowstart = tri(i);
    float fi       = f[i];

    for (; idx4 < end; idx4 += 256, te += 1024) {
        // advance over the inter-iteration jump (usually 0-2 rows; more only
        // in the short-row region, ~25% of elements)
        while (rowstart + i + 1 <= te) { rowstart += i + 1; ++i; }
        fi = f[i];

        float ov[4];
        int   rs = rowstart, ii = i;
        float fv = fi;
#pragma unroll
        for (int k = 0; k < 4; ++k) {
            const int e = te + k;
            while (rs + ii + 1 <= e) { rs += ii + 1; ++ii; fv = f[ii]; }
            ov[k] = fv * f[e - rs];
        }
        rowstart = rs; i = ii; fi = fv;            // persist in-group advances

        *reinterpret_cast<float4*>(otri + te) =
            make_float4(ov[0], ov[1], ov[2], ov[3]);   // aligned 16B store
    }
}

extern "C" void kernel_launch(void* const* d_in, const int* in_sizes, int n_in,
                              void* d_out, int out_size, void* d_ws, size_t ws_size,
                              hipStream_t stream) {
    const float* in  = (const float*)d_in[0];
    float*       out = (float*)d_out;
    const int grid = BATCH * CHUNKS;               // 2048 blocks, 8/CU
    hipLaunchKernelGGL(sideways_walk_kernel, dim3(grid), dim3(256), 0, stream,
                       in, out);
}

// Round 6
// 73.418 us; speedup vs baseline: 1.0680x; 1.0130x over previous
//
#include <hip/hip_runtime.h>

// SidewaysTime: out = concat(flat, tril(outer(flat,flat))) per batch sample.
// B=32, N=2048. Output = 268.8 MB fp32 -> pure store-BW bound.
// Fill ceiling ~6.9-7.1 TB/s; R3 row-pair kernel = 45.4 us = 5.92 TB/s.
//
// Structure lessons: row-pair mapping is right (R4 nt-stores and R5
// chunk-walker both regressed). This round: 8 consecutive row-pairs per
// block (grid 4096, 16 blocks/CU) — amortizes per-block prologue 8x and
// turns each block's stores into two long contiguous streams
// (rows [p0,p0+8) ascending and rows (N-1-p0-7..N-1-p0] descending).

#define BATCH      32
#define NFEAT      2048
#define TRI_COUNT  (NFEAT * (NFEAT + 1) / 2)      // 2,098,176
#define PER_BATCH  (NFEAT + TRI_COUNT)            // 2,100,224
#define PAIRS      (NFEAT / 2)                    // 1024 row-pairs per batch
#define PPB        8                              // pairs per block
#define BPB        (PAIRS / PPB)                  // 128 blocks per batch

__device__ __forceinline__ void do_row(const float* __restrict__ f,
                                       float* __restrict__ otri,  // ob + NFEAT
                                       int i, int t) {
    const float fi = f[i];                         // wave-uniform
    const int   S  = (i * (i + 1)) >> 1;           // row start within tril
    float* __restrict__ orow = otri + S;
    const int   L  = i + 1;                        // row length
    int h = (4 - (S & 3)) & 3;                     // head elems to 16B align
    if (h > L) h = L;
    if (t < h) orow[t] = fi * f[t];
    const int V = (L - h) >> 2;                    // float4 groups
    for (int v = t; v < V; v += 256) {
        const int j = h + (v << 2);
        float4 o = make_float4(fi * f[j],     fi * f[j + 1],
                               fi * f[j + 2], fi * f[j + 3]);
        *reinterpret_cast<float4*>(orow + j) = o;  // 16B-aligned store
    }
    const int done = h + (V << 2);
    if (t < L - done) {                            // tail (<=3)
        const int j = done + t;
        orow[j] = fi * f[j];
    }
}

__global__ void __launch_bounds__(256)
sideways_rows8_kernel(const float* __restrict__ in, float* __restrict__ out) {
    const int blk = blockIdx.x;
    const int b   = blk >> 7;                      // / BPB (128)
    const int p0  = (blk & (BPB - 1)) * PPB;       // first pair of this block
    const int t   = threadIdx.x;

    const float* __restrict__ f    = in + b * NFEAT;
    float* __restrict__       ob   = out + b * PER_BATCH;
    float* __restrict__       otri = ob + NFEAT;

    if (p0 == 0) {                                 // linear part, aligned
        for (int v = t; v < NFEAT / 4; v += 256)
            reinterpret_cast<float4*>(ob)[v] =
                reinterpret_cast<const float4*>(f)[v];
    }

#pragma unroll
    for (int q = 0; q < PPB; ++q) {
        do_row(f, otri, p0 + q, t);                // short rows: contiguous run
        do_row(f, otri, NFEAT - 1 - p0 - q, t);    // long rows: contiguous run
    }
}

extern "C" void kernel_launch(void* const* d_in, const int* in_sizes, int n_in,
                              void* d_out, int out_size, void* d_ws, size_t ws_size,
                              hipStream_t stream) {
    const float* in  = (const float*)d_in[0];
    float*       out = (float*)d_out;
    const int grid = BATCH * BPB;                  // 4096 blocks, 16/CU
    hipLaunchKernelGGL(sideways_rows8_kernel, dim3(grid), dim3(256), 0, stream,
                       in, out);
}

// Round 7
// 45.503 us; speedup vs baseline: 1.7232x; 1.6135x over previous
//
#include <hip/hip_runtime.h>

// SidewaysTime: out = concat(flat, tril(outer(flat,flat))) per batch sample.
// B=32, N=2048. Output = 268.8 MB fp32 -> pure store-BW bound.
//
// BEST STRUCTURE (R3, 45.4 us = 5.92 TB/s wall, ~6.4 TB/s ex-launch):
// one row-pair per 256-thread block, grid 32768. Rows p and N-1-p have
// constant combined length 2049. Many small independent waves keep the
// store queue saturated — measured better than:
//   - nontemporal stores          (R4: 78 us — nt bypasses L2 write combine)
//   - contiguous chunk-walker     (R5: 74 us — serial data-dependent walk)
//   - 8 pairs per block           (R6: 73 us — 8x fewer waves, serialized)
// Scalar-store version (R2) was 46.5 us — store width ~neutral; keep float4.

#define BATCH      32
#define NFEAT      2048
#define TRI_COUNT  (NFEAT * (NFEAT + 1) / 2)      // 2,098,176
#define PER_BATCH  (NFEAT + TRI_COUNT)            // 2,100,224
#define PAIRS      (NFEAT / 2)                    // 1024 row-pairs per batch

__device__ __forceinline__ void do_row(const float* __restrict__ f,
                                       float* __restrict__ otri,  // ob + NFEAT
                                       int i, int t) {
    const float fi = f[i];                         // wave-uniform
    const int   S  = (i * (i + 1)) >> 1;           // row start within tril
    float* __restrict__ orow = otri + S;
    const int   L  = i + 1;                        // row length
    int h = (4 - (S & 3)) & 3;                     // head elems to 16B align
    if (h > L) h = L;
    if (t < h) orow[t] = fi * f[t];
    const int V = (L - h) >> 2;                    // float4 groups
    for (int v = t; v < V; v += 256) {
        const int j = h + (v << 2);
        float4 o = make_float4(fi * f[j],     fi * f[j + 1],
                               fi * f[j + 2], fi * f[j + 3]);
        *reinterpret_cast<float4*>(orow + j) = o;  // 16B-aligned store
    }
    const int done = h + (V << 2);
    if (t < L - done) {                            // tail (<=3)
        const int j = done + t;
        orow[j] = fi * f[j];
    }
}

__global__ void __launch_bounds__(256)
sideways_rows_v4_kernel(const float* __restrict__ in, float* __restrict__ out) {
    const int blk = blockIdx.x;
    const int b   = blk >> 10;                     // / PAIRS
    const int p   = blk & (PAIRS - 1);
    const int t   = threadIdx.x;

    const float* __restrict__ f    = in + b * NFEAT;
    float* __restrict__       ob   = out + b * PER_BATCH;
    float* __restrict__       otri = ob + NFEAT;

    if (p == 0) {                                  // linear part, aligned
        for (int v = t; v < NFEAT / 4; v += 256)
            reinterpret_cast<float4*>(ob)[v] =
                reinterpret_cast<const float4*>(f)[v];
    }

    do_row(f, otri, p, t);                         // short row
    do_row(f, otri, NFEAT - 1 - p, t);             // long row
}

extern "C" void kernel_launch(void* const* d_in, const int* in_sizes, int n_in,
                              void* d_out, int out_size, void* d_ws, size_t ws_size,
                              hipStream_t stream) {
    const float* in  = (const float*)d_in[0];
    float*       out = (float*)d_out;
    const int grid = BATCH * PAIRS;                // 32768 blocks
    hipLaunchKernelGGL(sideways_rows_v4_kernel, dim3(grid), dim3(256), 0,
                       stream, in, out);
}